// Round 4
// baseline (2724.812 us; speedup 1.0000x reference)
//
#include <hip/hip_runtime.h>
#include <hip/hip_fp16.h>

// ---------------------------------------------------------------------------
// 2-layer LSTM (T=512, B=128, H=512) + linear head, persistent-kernel design.
// Round 14: XCD-local DATA path + proven agent-scope FLAG fabric.
//  - 8 groups x 16 batch rows, ONE GROUP PER XCD (HW_REG_XCC_ID self-assign).
//  - DATA: ring chunks written with global_atomic_swap_x2 (sc-less, executes
//    at the local XCD L2, bypasses L1/store buffers -> reliable publish;
//    round-13's plain stores were the corruption source). Consumers read
//    with sc0 loads (CU-L1 bypass, local-L2 hit ~200cy instead of LLC).
//  - FLAGS: round-10-proven fabric — releases are agent-scope RMW
//    (__hip_atomic_fetch_add AGENT, LLC-point), polls are agent-scope loads.
//    Order: swaps -> vmcnt(0) -> agent RMW  guarantees data@L2 before flag.
//  - Chunk-contiguous ring layout; single-wave store+drain+release tail;
//    x-part/bias hoisted before poll; bounded polls (failed verify, not hang).
// Roles per XCD/group: 0..7 = L1 block j (64 cols), 8..23 = L2 block j (32
// cols, kh-split waves). 384 blocks launched; role >= 24 exits immediately.
// ---------------------------------------------------------------------------

#define HDIM   512
#define TSTEPS 512
#define BATCH  128
#define DIN    5
#define NGRP   8      // one group per XCD
#define BROWS  16     // batch rows per group
#define NB1    8      // L1 blocks per group, 64 cols each
#define NB2    16     // L2 blocks per group, 32 cols each
#define RING   16
#define SPIN_CAP 65536

#define OFF_W1  0u            // L1 weights: 8 blocks * 256KB = 2MB
#define OFF_W2  2097152u      // L2 weights: 16 blocks * 256KB = 4MB
#define OFF_H1  6291456u      // h1 rings: 8 grp * 16 slots * 16KB = 2MB
#define OFF_H2  8388608u      // h2 rings: 8 grp * 2 slots * 16KB = 256KB
#define OFF_FL  8650752u      // flags: 8 grp * 48 lines * 128B = 48KB
#define WS_END  8699904u      // == round-10 proven footprint
// Flag lines per group (128B each, word p = producer p's step count):
//   line j      (j<8) : L1 block j's poll line      (8 L1 producer words)
//   line 8+j    (j<16): L2 block j's h1 line         (8 L1 producer words)
//   line 24+j   (j<16): L2 block j's h2 line         (16 L2 producer words)
//   line 40+j   (j<8) : L1 block j's back-pressure   (16 L2 producer words)
// Role counter for group g: line 0, word 31 (agent RMW; zeroed by init).
// h1 ring slot: 8 chunks x [16 rows][64 cols] fp16 (2KB/chunk, contiguous).
// h2 ring slot: 16 chunks x [16 rows][32 cols] fp16 (1KB/chunk, contiguous).

typedef _Float16 half8 __attribute__((ext_vector_type(8)));
typedef float    floatx4 __attribute__((ext_vector_type(4)));
typedef unsigned long long u64;

__device__ __forceinline__ float sigf(float v) { return 1.0f / (1.0f + __expf(-v)); }

__device__ __forceinline__ half8 as_h8(uint4 u) {
  union { uint4 u; half8 h; } c; c.u = u; return c.h;
}

__device__ __forceinline__ unsigned ld_xcc() {
  unsigned v;
  asm volatile("s_getreg_b32 %0, hwreg(HW_REG_XCC_ID)" : "=s"(v));
  return v & 7u;
}

// Data publish: 8B atomic swap, sc-less -> executes at the LOCAL XCD L2,
// bypasses L1/store buffers. vmcnt counts it; vmcnt(0) == committed at L2.
__device__ __forceinline__ void st8_swap(_Float16* p, u64 v) {
  asm volatile("global_atomic_swap_x2 %0, %1, off" :: "v"(p), "v"(v) : "memory");
}

// Flag release: agent-scope RMW at the LLC (round-10-proven flavor).
__device__ __forceinline__ void flag_add(unsigned* p) {
  __hip_atomic_fetch_add(p, 1u, __ATOMIC_RELAXED, __HIP_MEMORY_SCOPE_AGENT);
}

// Poll ONE private consumer line with agent-scope loads (round-10-proven).
// Bounded: a broken assumption costs ~ms and a failed verify, not a hang.
__device__ __forceinline__ void poll_line(const unsigned* line, int n, unsigned tgt,
                                          int lane) {
  for (int it = 0; it < SPIN_CAP; ++it) {
    unsigned v = tgt;
    if (lane < n)
      v = __hip_atomic_load(line + lane, __ATOMIC_RELAXED, __HIP_MEMORY_SCOPE_AGENT);
    if (__all((int)(v >= tgt))) break;
  }
  __asm__ __volatile__("" ::: "memory");
}

// 16 x 16B sc0 loads from h1-ring chunks ([16][64] fp16, 2KB stride), one wait.
// areg[ks]: chunk ks>>1 (2048B apart), col-half ks&1 (64B apart).
__device__ __forceinline__ void lda16a(const _Float16* b, uint4* a) {
  const _Float16* b0 = b;
  const _Float16* b1 = b + 2048;   // +4096B = chunk 2
  const _Float16* b2 = b + 4096;   // chunk 4
  const _Float16* b3 = b + 6144;   // chunk 6
  asm volatile(
      "global_load_dwordx4 %0, %16, off sc0\n\t"
      "global_load_dwordx4 %1, %16, off offset:64 sc0\n\t"
      "global_load_dwordx4 %2, %16, off offset:2048 sc0\n\t"
      "global_load_dwordx4 %3, %16, off offset:2112 sc0\n\t"
      "global_load_dwordx4 %4, %17, off sc0\n\t"
      "global_load_dwordx4 %5, %17, off offset:64 sc0\n\t"
      "global_load_dwordx4 %6, %17, off offset:2048 sc0\n\t"
      "global_load_dwordx4 %7, %17, off offset:2112 sc0\n\t"
      "global_load_dwordx4 %8, %18, off sc0\n\t"
      "global_load_dwordx4 %9, %18, off offset:64 sc0\n\t"
      "global_load_dwordx4 %10, %18, off offset:2048 sc0\n\t"
      "global_load_dwordx4 %11, %18, off offset:2112 sc0\n\t"
      "global_load_dwordx4 %12, %19, off sc0\n\t"
      "global_load_dwordx4 %13, %19, off offset:64 sc0\n\t"
      "global_load_dwordx4 %14, %19, off offset:2048 sc0\n\t"
      "global_load_dwordx4 %15, %19, off offset:2112 sc0\n\t"
      "s_waitcnt vmcnt(0)"
      : "=&v"(a[0]), "=&v"(a[1]), "=&v"(a[2]), "=&v"(a[3]),
        "=&v"(a[4]), "=&v"(a[5]), "=&v"(a[6]), "=&v"(a[7]),
        "=&v"(a[8]), "=&v"(a[9]), "=&v"(a[10]), "=&v"(a[11]),
        "=&v"(a[12]), "=&v"(a[13]), "=&v"(a[14]), "=&v"(a[15])
      : "v"(b0), "v"(b1), "v"(b2), "v"(b3)
      : "memory");
}

// Same for h2-ring chunks ([16][32] fp16, 1KB stride): areg[ks] = chunk ks.
__device__ __forceinline__ void lda16b(const _Float16* b, uint4* a) {
  const _Float16* b0 = b;
  const _Float16* b1 = b + 2048;   // +4096B = chunk 4
  const _Float16* b2 = b + 4096;   // chunk 8
  const _Float16* b3 = b + 6144;   // chunk 12
  asm volatile(
      "global_load_dwordx4 %0, %16, off sc0\n\t"
      "global_load_dwordx4 %1, %16, off offset:1024 sc0\n\t"
      "global_load_dwordx4 %2, %16, off offset:2048 sc0\n\t"
      "global_load_dwordx4 %3, %16, off offset:3072 sc0\n\t"
      "global_load_dwordx4 %4, %17, off sc0\n\t"
      "global_load_dwordx4 %5, %17, off offset:1024 sc0\n\t"
      "global_load_dwordx4 %6, %17, off offset:2048 sc0\n\t"
      "global_load_dwordx4 %7, %17, off offset:3072 sc0\n\t"
      "global_load_dwordx4 %8, %18, off sc0\n\t"
      "global_load_dwordx4 %9, %18, off offset:1024 sc0\n\t"
      "global_load_dwordx4 %10, %18, off offset:2048 sc0\n\t"
      "global_load_dwordx4 %11, %18, off offset:3072 sc0\n\t"
      "global_load_dwordx4 %12, %19, off sc0\n\t"
      "global_load_dwordx4 %13, %19, off offset:1024 sc0\n\t"
      "global_load_dwordx4 %14, %19, off offset:2048 sc0\n\t"
      "global_load_dwordx4 %15, %19, off offset:3072 sc0\n\t"
      "s_waitcnt vmcnt(0)"
      : "=&v"(a[0]), "=&v"(a[1]), "=&v"(a[2]), "=&v"(a[3]),
        "=&v"(a[4]), "=&v"(a[5]), "=&v"(a[6]), "=&v"(a[7]),
        "=&v"(a[8]), "=&v"(a[9]), "=&v"(a[10]), "=&v"(a[11]),
        "=&v"(a[12]), "=&v"(a[13]), "=&v"(a[14]), "=&v"(a[15])
      : "v"(b0), "v"(b1), "v"(b2), "v"(b3)
      : "memory");
}

// ---------------------------------------------------------------------------
extern "C" __global__ void init_kernel(char* __restrict__ ws, float* __restrict__ out,
                                       const float* __restrict__ blin) {
  unsigned tid = blockIdx.x * 256u + threadIdx.x;
  unsigned nz = (WS_END - OFF_H1) / 16u;  // rings + flags (incl. role counters)
  if (tid < nz) ((uint4*)(ws + OFF_H1))[tid] = make_uint4(0, 0, 0, 0);
  if (tid < (unsigned)(BATCH * TSTEPS)) out[tid] = blin[0];
}

// Pack fp32 weights -> fp16 MFMA B-fragment layout.
extern "C" __global__ void pack_kernel(const float* __restrict__ Whh1,
                                       const float* __restrict__ Wih2,
                                       const float* __restrict__ Whh2,
                                       char* __restrict__ ws) {
  unsigned tid = blockIdx.x * 256u + threadIdx.x;
  const float* src;
  char* dst;
  if (tid < 131072u) {
    // L1: j(8) x ch(4) x gg(4) x ks(16) x lane(64)
    unsigned lane = tid & 63u, ks = (tid >> 6) & 15u, gg = (tid >> 10) & 3u,
             ch = (tid >> 12) & 3u, j = tid >> 14;
    unsigned cg = j * 64u + ch * 16u + (lane & 15u);
    unsigned row = gg * 512u + cg;
    unsigned k0 = ks * 32u + (lane >> 4) * 8u;
    src = Whh1 + (size_t)row * 512u + k0;
    dst = ws + OFF_W1 + (size_t)tid * 16u;
  } else {
    unsigned t2 = tid - 131072u;
    if (t2 >= 262144u) return;
    // L2: j(16) x wave(4: kh=wv&1, ch=wv>>1) x gg(4) x ks(16) x lane(64)
    unsigned lane = t2 & 63u, ks = (t2 >> 6) & 15u, gg = (t2 >> 10) & 3u,
             wv = (t2 >> 12) & 3u, j = t2 >> 14;
    unsigned kh = wv & 1u, ch = wv >> 1;
    unsigned cg = j * 32u + ch * 16u + (lane & 15u);
    unsigned row = gg * 512u + cg;
    unsigned kp = kh * 512u + ks * 32u + (lane >> 4) * 8u;
    src = (kp < 512u) ? (Wih2 + (size_t)row * 512u + kp)
                      : (Whh2 + (size_t)row * 512u + (kp - 512u));
    dst = ws + OFF_W2 + (size_t)t2 * 16u;
  }
  float4 lo = ((const float4*)src)[0];
  float4 hi = ((const float4*)src)[1];
  _Float16 v[8] = {(_Float16)lo.x, (_Float16)lo.y, (_Float16)lo.z, (_Float16)lo.w,
                   (_Float16)hi.x, (_Float16)hi.y, (_Float16)hi.z, (_Float16)hi.w};
  *(uint4*)dst = *(const uint4*)v;
}

// ---------------------------------------------------------------------------
extern "C" __global__ __launch_bounds__(256, 1) void lstm_persist(
    const float* __restrict__ x,
    const float* __restrict__ Wih1,
    const float* __restrict__ bih1, const float* __restrict__ bhh1,
    const float* __restrict__ bih2, const float* __restrict__ bhh2,
    const float* __restrict__ Wlin,
    float* __restrict__ out,
    char* __restrict__ ws) {
  __shared__ char smem[16384];
  __shared__ unsigned role_s;

  // --- hardware-placement self-assignment: group = my XCD ---
  const unsigned xcc = ld_xcc();
  unsigned* fl = (unsigned*)(ws + OFF_FL) + (size_t)xcc * 48 * 32;
  if (threadIdx.x == 0)
    role_s = __hip_atomic_fetch_add(fl + 31, 1u, __ATOMIC_RELAXED,
                                    __HIP_MEMORY_SCOPE_AGENT);
  __syncthreads();
  const unsigned role = role_s;
  if (role >= (unsigned)(NB1 + NB2)) return;

  const int g = (int)xcc;
  const int tid = threadIdx.x;
  const int wave = tid >> 6;
  const int lane = tid & 63;
  const int nlane = lane & 15;
  const int quad = lane >> 4;

  _Float16* ring1 = (_Float16*)(ws + OFF_H1) + (size_t)g * (RING * 8192);
  _Float16* ring2 = (_Float16*)(ws + OFF_H2) + (size_t)g * (2 * 8192);

  if (role < NB1) {
    // ------------------------------ layer 1 -------------------------------
    const int j = (int)role;
    const char* gW = ws + OFF_W1 + (size_t)j * 262144u;
    const unsigned* myline = fl + (size_t)j * 32;         // 8 L1 producers
    const unsigned* mybp = fl + (size_t)(40 + j) * 32;    // 16 L2 producers
    _Float16* tile = (_Float16*)smem;                     // [16][64] fp16 = 2KB

    const int ch = wave;                                  // 16-col slice
    const int cg = j * 64 + ch * 16 + nlane;

    half8 breg[64];                                       // register-resident B
#pragma unroll
    for (int r = 0; r < 64; ++r)
      breg[r] = *(const half8*)(gW + (size_t)(ch * 64 + r) * 1024 + lane * 16);

    float bias_r[4], wih[4][DIN];
    for (int gg = 0; gg < 4; ++gg) {
      int row = gg * 512 + cg;
      bias_r[gg] = bih1[row] + bhh1[row];
      for (int k = 0; k < DIN; ++k) wih[gg][k] = Wih1[row * DIN + k];
    }
    float cstate[4] = {};

    for (int t = 0; t < TSTEPS; ++t) {
      // x-part + bias acc-init FIRST (independent of flags; hides under poll)
      float xr[4][DIN];
#pragma unroll
      for (int r = 0; r < 4; ++r) {
        int b = g * BROWS + quad * 4 + r;
        const float* xp = x + ((size_t)t * BATCH + b) * DIN;
#pragma unroll
        for (int k = 0; k < DIN; ++k) xr[r][k] = xp[k];
      }
      floatx4 acc[4];
#pragma unroll
      for (int gg = 0; gg < 4; ++gg) {
#pragma unroll
        for (int r = 0; r < 4; ++r) {
          float s = bias_r[gg];
#pragma unroll
          for (int k = 0; k < DIN; ++k) s += xr[r][k] * wih[gg][k];
          acc[gg][r] = s;
        }
      }
      // acquire peers' h1(t-1); amortized back-pressure on ring overwrite
      if (t) poll_line(myline, NB1, (unsigned)t, lane);
      if ((t & 7) == 0 && t >= RING) poll_line(mybp, NB2, (unsigned)(t - 8), lane);

      uint4 areg[16];
      lda16a(ring1 + (size_t)((t + RING - 1) & (RING - 1)) * 8192 +
                 nlane * 64 + quad * 8,
             areg);

#pragma unroll
      for (int ks = 0; ks < 16; ++ks) {
        half8 av = as_h8(areg[ks]);
#pragma unroll
        for (int gg = 0; gg < 4; ++gg)
          acc[gg] = __builtin_amdgcn_mfma_f32_16x16x32_f16(av, breg[gg * 16 + ks],
                                                           acc[gg], 0, 0, 0);
      }
#pragma unroll
      for (int r = 0; r < 4; ++r) {
        float iv = acc[0][r], fv = acc[1][r], gv = acc[2][r], ov = acc[3][r];
        float cn = sigf(fv) * cstate[r] + sigf(iv) * tanhf(gv);
        float hn = sigf(ov) * tanhf(cn);
        cstate[r] = cn;
        tile[(quad * 4 + r) * 64 + ch * 16 + nlane] = (_Float16)hn;
      }
      __syncthreads();
      // single-wave publish: swap-stores (local L2) + drain + agent release
      if (wave == 0) {
        const int row = lane >> 2, c16 = (lane & 3) * 16;
        const u64* tp = (const u64*)(tile + row * 64 + c16);
        _Float16* dp = ring1 + (size_t)(t & (RING - 1)) * 8192 + j * 1024 +
                       row * 64 + c16;
        st8_swap(dp,      tp[0]);
        st8_swap(dp + 4,  tp[1]);
        st8_swap(dp + 8,  tp[2]);
        st8_swap(dp + 12, tp[3]);
        asm volatile("s_waitcnt vmcnt(0)" ::: "memory");
        if (lane < 24) flag_add(fl + (size_t)lane * 32 + j);  // lines 0..23
      }
      // next-step tile writes are gated by poll(own flag) -> no trailing barrier
    }
  } else {
    // ------------------------------ layer 2 -------------------------------
    const int j = (int)role - NB1;
    const char* gW = ws + OFF_W2 + (size_t)j * 262144u;
    const unsigned* l_h1 = fl + (size_t)(8 + j) * 32;     // 8 L1 producers
    const unsigned* l_h2 = fl + (size_t)(24 + j) * 32;    // 16 L2 producers
    floatx4* pbase = (floatx4*)smem;                      // 8KB partials
    _Float16* tile2 = (_Float16*)(smem + 8192);           // [16][32] fp16 = 1KB

    const int kh = wave & 1;   // 0 -> W_ih2 . h1(t), 1 -> W_hh2 . h2(t-1)
    const int ch = wave >> 1;  // 16-col slice
    const int cg = j * 32 + ch * 16 + nlane;

    half8 breg[64];
#pragma unroll
    for (int r = 0; r < 64; ++r)
      breg[r] = *(const half8*)(gW + (size_t)(wave * 64 + r) * 1024 + lane * 16);

    float bias_r[4];
    for (int gg = 0; gg < 4; ++gg) {
      int row = gg * 512 + cg;
      bias_r[gg] = bih2[row] + bhh2[row];
    }
    const float wl = Wlin[cg];
    float cstate[4] = {};

    for (int t = 0; t < TSTEPS; ++t) {
      uint4 areg[16];
      if (kh == 0) {
        // h1(t): L1 runs ahead, this rarely waits
        poll_line(l_h1, NB1, (unsigned)(t + 1), lane);
        lda16a(ring1 + (size_t)(t & (RING - 1)) * 8192 + nlane * 64 + quad * 8,
               areg);
      } else {
        // h2(t-1): the critical self-recurrence
        if (t) poll_line(l_h2, NB2, (unsigned)t, lane);
        lda16b(ring2 + (size_t)((t + 1) & 1) * 8192 + nlane * 32 + quad * 8,
               areg);
      }
      floatx4 acc[4];
#pragma unroll
      for (int gg = 0; gg < 4; ++gg)
        acc[gg] = (kh == 0)
            ? (floatx4){bias_r[gg], bias_r[gg], bias_r[gg], bias_r[gg]}
            : (floatx4){0.f, 0.f, 0.f, 0.f};
#pragma unroll
      for (int ks = 0; ks < 16; ++ks) {
        half8 av = as_h8(areg[ks]);
#pragma unroll
        for (int gg = 0; gg < 4; ++gg)
          acc[gg] = __builtin_amdgcn_mfma_f32_16x16x32_f16(av, breg[gg * 16 + ks],
                                                           acc[gg], 0, 0, 0);
      }
      if (kh == 1) {
#pragma unroll
        for (int gg = 0; gg < 4; ++gg) pbase[(ch * 4 + gg) * 64 + lane] = acc[gg];
      }
      __syncthreads();  // A: pbase ready
      float red[4];
      if (kh == 0) {
#pragma unroll
        for (int gg = 0; gg < 4; ++gg) acc[gg] += pbase[(ch * 4 + gg) * 64 + lane];
#pragma unroll
        for (int r = 0; r < 4; ++r) {
          float iv = acc[0][r], fv = acc[1][r], gv = acc[2][r], ov = acc[3][r];
          float cn = sigf(fv) * cstate[r] + sigf(iv) * tanhf(gv);
          float hn = sigf(ov) * tanhf(cn);
          cstate[r] = cn;
          tile2[(quad * 4 + r) * 32 + ch * 16 + nlane] = (_Float16)hn;
          red[r] = wl * hn;
        }
      }
      __syncthreads();  // B: tile2 ready
      // single-wave publish: swap-stores (local L2) + drain + agent release
      if (wave == 0) {
        const int row = lane >> 2, c8 = (lane & 3) * 8;
        const u64* tp = (const u64*)(tile2 + row * 32 + c8);
        _Float16* dp = ring2 + (size_t)(t & 1) * 8192 + j * 512 + row * 32 + c8;
        st8_swap(dp,     tp[0]);
        st8_swap(dp + 4, tp[1]);
        asm volatile("s_waitcnt vmcnt(0)" ::: "memory");
        if (lane < 24) flag_add(fl + (size_t)(24 + lane) * 32 + j);  // 24..47
      }
      // linear head: fire-and-forget, off the critical path
      if (kh == 0) {
#pragma unroll
        for (int r = 0; r < 4; ++r) {
          float v2 = red[r];
          v2 += __shfl_xor(v2, 1, 64);
          v2 += __shfl_xor(v2, 2, 64);
          v2 += __shfl_xor(v2, 4, 64);
          v2 += __shfl_xor(v2, 8, 64);
          red[r] = v2;
        }
        if (nlane == 0) {
#pragma unroll
          for (int r = 0; r < 4; ++r) {
            int b = g * BROWS + quad * 4 + r;
            atomicAdd(out + (size_t)b * TSTEPS + t, red[r]);
          }
        }
      }
    }
  }
}

// ---------------------------------------------------------------------------
extern "C" void kernel_launch(void* const* d_in, const int* in_sizes, int n_in,
                              void* d_out, int out_size, void* d_ws, size_t ws_size,
                              hipStream_t stream) {
  const float* x    = (const float*)d_in[0];
  const float* Wih1 = (const float*)d_in[1];
  const float* Whh1 = (const float*)d_in[2];
  const float* bih1 = (const float*)d_in[3];
  const float* bhh1 = (const float*)d_in[4];
  const float* Wih2 = (const float*)d_in[5];
  const float* Whh2 = (const float*)d_in[6];
  const float* bih2 = (const float*)d_in[7];
  const float* bhh2 = (const float*)d_in[8];
  const float* Wlin = (const float*)d_in[9];
  const float* blin = (const float*)d_in[10];
  float* out = (float*)d_out;
  char* ws = (char*)d_ws;

  init_kernel<<<640, 256, 0, stream>>>(ws, out, blin);
  pack_kernel<<<1536, 256, 0, stream>>>(Whh1, Wih2, Whh2, ws);
  // 384 blocks: each XCD claims 24 workers (8 L1 + 16 L2); the rest exit.
  lstm_persist<<<384, 256, 0, stream>>>(x, Wih1, bih1, bhh1, bih2, bhh2, Wlin, out, ws);
}

// Round 7
// 2523.467 us; speedup vs baseline: 1.0798x; 1.0798x over previous
//
#include <hip/hip_runtime.h>
#include <hip/hip_fp16.h>

// ---------------------------------------------------------------------------
// 2-layer LSTM (T=512, B=128, H=512) + linear head, persistent-kernel design.
// Round 17: round 16 + EARLY-CLOBBER fix in lda16.
//  - Rounds 15/16 core-dumped (GPU aperture fault): lda16 used "=v" outputs
//    with the address input %16 -> LLVM may overlap an output reg pair with
//    the address pair (inputs assumed dead before outputs written); later
//    loads then use a corrupted address. Round 10 passed on lucky regalloc;
//    the poll_ctrs change reshuffled allocation into the hazard. Fix: "=&v".
//  - Geometry/data path IDENTICAL to round 10 (proven 2318us): 4 groups x 32
//    batch rows, L1 on xcd g+4 (16 blocks x 32 cols), L2 on xcd g (32 blocks
//    x 16 cols), agent-scope ring stores, sc0sc1 lda16 reads, 2 barriers.
//  - ONE perf change vs round 10: producer-owned flag counters. Round 10's
//    48 per-consumer-line RMWs -> each consumer line absorbed 16-32
//    same-line LLC-serialized RMWs/step (~2k cy tail on the recurrence).
//    Now each producer RMWs ONE private 64B line; consumers poll N producer
//    lines (lane i -> line i). Zero write-side line sharing.
//  - Release invariant preserved: stores drained by barrier, then agent RMW
//    release; agent-scope polls (the only flavor that never corrupted).
//  - x-loads/bias-init hoisted before polls. SPIN_CAP=16384 (bounded).
// ---------------------------------------------------------------------------

#define HDIM   512
#define TSTEPS 512
#define BATCH  128
#define DIN    5
#define NGRP   4
#define MGRP   32
#define NB1    16
#define NB2    32
#define RING   16
#define SPIN_CAP 16384

#define OFF_W1 0u            // packed layer1 weights: 16 blocks * 128KB = 2MB
#define OFF_W2 2097152u      // packed layer2 weights: 32 blocks * 128KB = 4MB
#define OFF_H1 6291456u      // h1 ring: 4 * 16 * 32 * 512 fp16 = 2MB
#define OFF_H2 8388608u      // h2 ring: 4 * 2 * 32 * 512 fp16 = 256KB
#define OFF_CT 8650752u      // producer counters: 4 grp * 6KB
#define WS_END 8699904u      // == round-10 proven footprint
// Counter layout per group g (base = OFF_CT + g*6144, 64B per counter):
//   words [j*16]        j<16 : L1 producer j's step count
//   words [256 + j*16]  j<32 : L2 producer j's step count
// Consumers poll with lane i -> counter i (64B-strided 4B loads).

typedef _Float16 half8 __attribute__((ext_vector_type(8)));
typedef float    floatx4 __attribute__((ext_vector_type(4)));
typedef unsigned long long u64;

__device__ __forceinline__ float sigf(float v) { return 1.0f / (1.0f + __expf(-v)); }

__device__ __forceinline__ half8 as_h8(uint4 u) {
  union { uint4 u; half8 h; } c; c.u = u; return c.h;
}
__device__ __forceinline__ void ring_st8(_Float16* p, u64 v) {
  __hip_atomic_store((u64*)p, v, __ATOMIC_RELAXED, __HIP_MEMORY_SCOPE_AGENT);
}
// Producer release: ONE non-returning agent RMW to a private 64B line.
__device__ __forceinline__ void flag_add(unsigned* p) {
  __hip_atomic_fetch_add(p, 1u, __ATOMIC_RELAXED, __HIP_MEMORY_SCOPE_AGENT);
}
// Poll producer counters: lane i (<n) reads counter i (64B apart).
// Bounded: a broken assumption costs ~ms + failed verify, not a hang.
__device__ __forceinline__ void poll_ctrs(const unsigned* base, int n, unsigned tgt,
                                          int lane) {
  for (int it = 0; it < SPIN_CAP; ++it) {
    unsigned v = tgt;
    if (lane < n)
      v = __hip_atomic_load(base + (size_t)lane * 16, __ATOMIC_RELAXED,
                            __HIP_MEMORY_SCOPE_AGENT);
    if (__all((int)(v >= tgt))) break;
  }
  __asm__ __volatile__("" ::: "memory");
}
// 16 pipelined 16B agent-coherent loads (sc0 sc1), ONE waitcnt.
// "=&v" early-clobber: outputs must NOT share regs with the %16 address pair
// (the asm reads %16 after writing outputs). "=v" here caused the r15/r16
// aperture faults.
__device__ __forceinline__ void lda16(const _Float16* p, uint4* a) {
  asm volatile(
      "global_load_dwordx4 %0, %16, off sc0 sc1\n\t"
      "global_load_dwordx4 %1, %16, off offset:64 sc0 sc1\n\t"
      "global_load_dwordx4 %2, %16, off offset:128 sc0 sc1\n\t"
      "global_load_dwordx4 %3, %16, off offset:192 sc0 sc1\n\t"
      "global_load_dwordx4 %4, %16, off offset:256 sc0 sc1\n\t"
      "global_load_dwordx4 %5, %16, off offset:320 sc0 sc1\n\t"
      "global_load_dwordx4 %6, %16, off offset:384 sc0 sc1\n\t"
      "global_load_dwordx4 %7, %16, off offset:448 sc0 sc1\n\t"
      "global_load_dwordx4 %8, %16, off offset:512 sc0 sc1\n\t"
      "global_load_dwordx4 %9, %16, off offset:576 sc0 sc1\n\t"
      "global_load_dwordx4 %10, %16, off offset:640 sc0 sc1\n\t"
      "global_load_dwordx4 %11, %16, off offset:704 sc0 sc1\n\t"
      "global_load_dwordx4 %12, %16, off offset:768 sc0 sc1\n\t"
      "global_load_dwordx4 %13, %16, off offset:832 sc0 sc1\n\t"
      "global_load_dwordx4 %14, %16, off offset:896 sc0 sc1\n\t"
      "global_load_dwordx4 %15, %16, off offset:960 sc0 sc1\n\t"
      "s_waitcnt vmcnt(0)"
      : "=&v"(a[0]), "=&v"(a[1]), "=&v"(a[2]), "=&v"(a[3]),
        "=&v"(a[4]), "=&v"(a[5]), "=&v"(a[6]), "=&v"(a[7]),
        "=&v"(a[8]), "=&v"(a[9]), "=&v"(a[10]), "=&v"(a[11]),
        "=&v"(a[12]), "=&v"(a[13]), "=&v"(a[14]), "=&v"(a[15])
      : "v"(p)
      : "memory");
}

// ---------------------------------------------------------------------------
extern "C" __global__ void init_kernel(char* __restrict__ ws, float* __restrict__ out,
                                       const float* __restrict__ blin) {
  unsigned tid = blockIdx.x * 256u + threadIdx.x;
  unsigned nz = (WS_END - OFF_H1) / 16u;
  if (tid < nz) ((uint4*)(ws + OFF_H1))[tid] = make_uint4(0, 0, 0, 0);
  if (tid < (unsigned)(BATCH * TSTEPS)) out[tid] = blin[0];
}

// Pack fp32 weights -> fp16 MFMA B-fragment layout (round-10, unchanged).
extern "C" __global__ void pack_kernel(const float* __restrict__ Whh1,
                                       const float* __restrict__ Wih2,
                                       const float* __restrict__ Whh2,
                                       char* __restrict__ ws) {
  unsigned tid = blockIdx.x * 256u + threadIdx.x;
  const float* src;
  char* dst;
  if (tid < 131072u) {
    unsigned lane = tid & 63u, ks = (tid >> 6) & 15u, gg = (tid >> 10) & 3u,
             h = (tid >> 12) & 1u, j = tid >> 13;
    unsigned cg = j * 32u + h * 16u + (lane & 15u);
    unsigned row = gg * 512u + cg;
    unsigned k0 = ks * 32u + (lane >> 4) * 8u;
    src = Whh1 + (size_t)row * 512u + k0;
    dst = ws + OFF_W1 + (size_t)tid * 16u;
  } else {
    unsigned t2 = tid - 131072u;
    if (t2 >= 262144u) return;
    unsigned lane = t2 & 63u, ksl = (t2 >> 6) & 15u, gg = (t2 >> 10) & 3u,
             kh = (t2 >> 12) & 1u, j = t2 >> 13;
    unsigned cg = j * 16u + (lane & 15u);
    unsigned row = gg * 512u + cg;
    unsigned kp = kh * 512u + ksl * 32u + (lane >> 4) * 8u;
    src = (kp < 512u) ? (Wih2 + (size_t)row * 512u + kp)
                      : (Whh2 + (size_t)row * 512u + (kp - 512u));
    dst = ws + OFF_W2 + (size_t)t2 * 16u;
  }
  float4 lo = ((const float4*)src)[0];
  float4 hi = ((const float4*)src)[1];
  _Float16 v[8] = {(_Float16)lo.x, (_Float16)lo.y, (_Float16)lo.z, (_Float16)lo.w,
                   (_Float16)hi.x, (_Float16)hi.y, (_Float16)hi.z, (_Float16)hi.w};
  *(uint4*)dst = *(const uint4*)v;
}

// ---------------------------------------------------------------------------
extern "C" __global__ __launch_bounds__(256, 1) void lstm_persist(
    const float* __restrict__ x,
    const float* __restrict__ Wih1,
    const float* __restrict__ bih1, const float* __restrict__ bhh1,
    const float* __restrict__ bih2, const float* __restrict__ bhh2,
    const float* __restrict__ Wlin,
    float* __restrict__ out,
    char* __restrict__ ws) {
  __shared__ char smem[16384];

  const int blk = blockIdx.x;
  const int xcd = blk & 7;
  const int slot = blk >> 3;
  const int tid = threadIdx.x;
  const int wave = tid >> 6;
  const int lane = tid & 63;
  const int nlane = lane & 15;
  const int quad = lane >> 4;

  _Float16* h1ring = (_Float16*)(ws + OFF_H1);
  _Float16* h2ring = (_Float16*)(ws + OFF_H2);

  if (xcd >= NGRP) {
    // ------------------------------ layer 1 -------------------------------
    const int g = xcd - NGRP;
    const int j = slot;
    if (j >= NB1) return;
    const char* gW = ws + OFF_W1 + (size_t)j * 131072u;

    unsigned* cbase = (unsigned*)(ws + OFF_CT) + (size_t)g * 1536;  // 6KB/grp
    const unsigned* ctL1 = cbase;          // 16 counters, 64B apart
    const unsigned* ctL2 = cbase + 256;    // 32 counters, 64B apart
    _Float16* ring = h1ring + (size_t)g * (RING * MGRP * HDIM);
    _Float16* tile = (_Float16*)smem;  // 32x32 fp16 = 2KB

    const int mt = wave >> 1;  // batch half (16 rows)
    const int hh = wave & 1;   // column half (16 cols)
    const int cg = j * 32 + hh * 16 + nlane;

    // persistent B-slice: 64 rows x 16B/lane = 256 VGPRs, loaded once
    half8 breg[64];
#pragma unroll
    for (int r = 0; r < 64; ++r)
      breg[r] = *(const half8*)(gW + (size_t)((hh * 64 + r) * 64 + lane) * 16);

    float bias_r[4], wih[4][5];
    for (int gg = 0; gg < 4; ++gg) {
      int row = gg * 512 + cg;
      bias_r[gg] = bih1[row] + bhh1[row];
      for (int k = 0; k < 5; ++k) wih[gg][k] = Wih1[row * 5 + k];
    }
    float cstate[4] = {};

    for (int t = 0; t < TSTEPS; ++t) {
      // x-part + bias acc-init FIRST (independent of flags; hides under poll)
      float xr[4][5];
#pragma unroll
      for (int r = 0; r < 4; ++r) {
        int b = g * MGRP + mt * 16 + quad * 4 + r;
        const float* xp = x + ((size_t)t * BATCH + b) * DIN;
#pragma unroll
        for (int k = 0; k < 5; ++k) xr[r][k] = xp[k];
      }
      floatx4 acc[4];
#pragma unroll
      for (int gg = 0; gg < 4; ++gg) {
#pragma unroll
        for (int r = 0; r < 4; ++r) {
          float s = bias_r[gg];
#pragma unroll
          for (int k = 0; k < 5; ++k) s += xr[r][k] * wih[gg][k];
          acc[gg][r] = s;
        }
      }
      // acquire: peers' h1(t-1); amortized ring back-pressure
      if (t) poll_ctrs(ctL1, NB1, (unsigned)t, lane);
      if ((t & 7) == 0 && t >= 16) poll_ctrs(ctL2, NB2, (unsigned)(t - 8), lane);

      // batched A-fragment loads: 16 x 16B, one waitcnt
      const _Float16* ap =
          ring + (size_t)((t + RING - 1) & (RING - 1)) * (MGRP * HDIM) +
          mt * 16 * HDIM + nlane * HDIM + quad * 8;
      uint4 areg[16];
      lda16(ap, areg);

      // 64 register-fed MFMAs
#pragma unroll
      for (int ks = 0; ks < 16; ++ks) {
        half8 av = as_h8(areg[ks]);
#pragma unroll
        for (int gg = 0; gg < 4; ++gg)
          acc[gg] = __builtin_amdgcn_mfma_f32_16x16x32_f16(av, breg[gg * 16 + ks],
                                                           acc[gg], 0, 0, 0);
      }
      // gates -> LDS transpose tile (32 rows x 32 cols fp16)
#pragma unroll
      for (int r = 0; r < 4; ++r) {
        float iv = acc[0][r], fv = acc[1][r], gv = acc[2][r], ov = acc[3][r];
        float cn = sigf(fv) * cstate[r] + sigf(iv) * tanhf(gv);
        float hn = sigf(ov) * tanhf(cn);
        cstate[r] = cn;
        tile[(mt * 16 + quad * 4 + r) * 32 + hh * 16 + nlane] = (_Float16)hn;
      }
      __syncthreads();
      // ring store: 256 threads x 8B, coalesced, agent-coherent
      {
        _Float16* hout = ring + (size_t)(t & (RING - 1)) * (MGRP * HDIM);
        u64 v = *(const u64*)(tile + (tid >> 3) * 32 + (tid & 7) * 4);
        ring_st8(hout + (tid >> 3) * HDIM + j * 32 + (tid & 7) * 4, v);
      }
      __syncthreads();  // drains vmcnt: all stores globally visible (R7-proven)
      // release: ONE non-returning RMW to the producer-private counter
      if (tid == 0) flag_add(cbase + (size_t)j * 16);
    }
  } else {
    // ------------------------------ layer 2 -------------------------------
    const int g = xcd;
    const int j = slot;
    const char* gW = ws + OFF_W2 + (size_t)j * 131072u;

    unsigned* cbase = (unsigned*)(ws + OFF_CT) + (size_t)g * 1536;
    const unsigned* ctL1 = cbase;
    const unsigned* ctL2 = cbase + 256;
    const _Float16* h1rd = h1ring + (size_t)g * (RING * MGRP * HDIM);
    _Float16* ring2 = h2ring + (size_t)g * (2 * MGRP * HDIM);
    floatx4* pbase = (floatx4*)smem;                 // 8KB
    _Float16* tile2 = (_Float16*)(smem + 8192);      // 32x16 fp16 = 1KB

    const int kh = wave & 1;   // 0 -> W_ih2 . h1(t), 1 -> W_hh2 . h2(t-1)
    const int mt = wave >> 1;  // batch half
    const int cg = j * 16 + nlane;

    // persistent B-slice: 64 rows x 16B/lane = 256 VGPRs, loaded once
    half8 breg[64];
#pragma unroll
    for (int r = 0; r < 64; ++r)
      breg[r] = *(const half8*)(gW + (size_t)((kh * 64 + r) * 64 + lane) * 16);

    float bias_r[4];
    for (int gg = 0; gg < 4; ++gg) {
      int row = gg * 512 + cg;
      bias_r[gg] = bih2[row] + bhh2[row];
    }
    const float wl = Wlin[cg];
    float cstate[4] = {};

    for (int t = 0; t < TSTEPS; ++t) {
      // acquire: kh0 needs h1(t) (>= t+1); kh1 needs peers' h2(t-1) (>= t)
      if (kh == 0) poll_ctrs(ctL1, NB1, (unsigned)(t + 1), lane);
      else if (t)  poll_ctrs(ctL2, NB2, (unsigned)t, lane);

      const _Float16* abase = (kh == 0)
          ? h1rd + (size_t)(t & (RING - 1)) * (MGRP * HDIM) + mt * 16 * HDIM +
                nlane * HDIM + quad * 8
          : ring2 + (size_t)((t + 1) & 1) * (MGRP * HDIM) + mt * 16 * HDIM +
                nlane * HDIM + quad * 8;
      uint4 areg[16];
      lda16(abase, areg);

      floatx4 acc[4];
#pragma unroll
      for (int gg = 0; gg < 4; ++gg)
        acc[gg] = (kh == 0)
            ? (floatx4){bias_r[gg], bias_r[gg], bias_r[gg], bias_r[gg]}
            : (floatx4){0.f, 0.f, 0.f, 0.f};
#pragma unroll
      for (int ks = 0; ks < 16; ++ks) {
        half8 av = as_h8(areg[ks]);
#pragma unroll
        for (int gg = 0; gg < 4; ++gg)
          acc[gg] = __builtin_amdgcn_mfma_f32_16x16x32_f16(av, breg[gg * 16 + ks],
                                                           acc[gg], 0, 0, 0);
      }
      if (kh == 1) {
#pragma unroll
        for (int gg = 0; gg < 4; ++gg) pbase[(mt * 4 + gg) * 64 + lane] = acc[gg];
      }
      __syncthreads();
      float red[4];
      if (kh == 0) {
#pragma unroll
        for (int gg = 0; gg < 4; ++gg) acc[gg] += pbase[(mt * 4 + gg) * 64 + lane];
#pragma unroll
        for (int r = 0; r < 4; ++r) {
          float iv = acc[0][r], fv = acc[1][r], gv = acc[2][r], ov = acc[3][r];
          float cn = sigf(fv) * cstate[r] + sigf(iv) * tanhf(gv);
          float hn = sigf(ov) * tanhf(cn);
          cstate[r] = cn;
          tile2[(mt * 16 + quad * 4 + r) * 16 + nlane] = (_Float16)hn;
          red[r] = wl * hn;
        }
      }
      __syncthreads();
      // ring2 store: 128 threads x 8B
      if (tid < 128) {
        u64 v = *(const u64*)(tile2 + (tid >> 2) * 16 + (tid & 3) * 4);
        ring_st8(ring2 + (size_t)(t & 1) * (MGRP * HDIM) + (tid >> 2) * HDIM +
                     j * 16 + (tid & 3) * 4, v);
      }
      __syncthreads();  // drains vmcnt before release
      // release: ONE non-returning RMW to the producer-private counter
      if (tid == 0) flag_add(cbase + (size_t)(256 + j * 16));
      // linear head: fire-and-forget, off the critical path
      if (kh == 0) {
#pragma unroll
        for (int r = 0; r < 4; ++r) {
          float v2 = red[r];
          v2 += __shfl_xor(v2, 1, 64);
          v2 += __shfl_xor(v2, 2, 64);
          v2 += __shfl_xor(v2, 4, 64);
          v2 += __shfl_xor(v2, 8, 64);
          red[r] = v2;
        }
        if (nlane == 0) {
#pragma unroll
          for (int r = 0; r < 4; ++r) {
            int b = g * MGRP + mt * 16 + quad * 4 + r;
            atomicAdd(out + (size_t)b * TSTEPS + t, red[r]);
          }
        }
      }
    }
  }
}

// ---------------------------------------------------------------------------
extern "C" void kernel_launch(void* const* d_in, const int* in_sizes, int n_in,
                              void* d_out, int out_size, void* d_ws, size_t ws_size,
                              hipStream_t stream) {
  const float* x    = (const float*)d_in[0];
  const float* Wih1 = (const float*)d_in[1];
  const float* Whh1 = (const float*)d_in[2];
  const float* bih1 = (const float*)d_in[3];
  const float* bhh1 = (const float*)d_in[4];
  const float* Wih2 = (const float*)d_in[5];
  const float* Whh2 = (const float*)d_in[6];
  const float* bih2 = (const float*)d_in[7];
  const float* bhh2 = (const float*)d_in[8];
  const float* Wlin = (const float*)d_in[9];
  const float* blin = (const float*)d_in[10];
  float* out = (float*)d_out;
  char* ws = (char*)d_ws;

  init_kernel<<<640, 256, 0, stream>>>(ws, out, blin);
  pack_kernel<<<1536, 256, 0, stream>>>(Whh1, Wih2, Whh2, ws);
  lstm_persist<<<256, 256, 0, stream>>>(x, Wih1, bih1, bhh1, bih2, bhh2, Wlin, out, ws);
}